// Round 1
// baseline (5762.819 us; speedup 1.0000x reference)
//
#include <hip/hip_runtime.h>
#include <math.h>

#define N_NODES 50000
#define E_EDGES 800000
#define DIM 256      // IN_DIM = HID = 256 (= H*O for both layers)
#define HEADS 4
#define HO 64        // per-head output width (O1 = LAT = 64)
#define NEG_SLOPE 0.2f

// ---------------- GEMM: C = A(M x 256) @ B(256 x 256), row-major ----------------
#define BM 64
#define BN 64
#define BK 16

__global__ __launch_bounds__(256) void gemm256(const float* __restrict__ A,
                                               const float* __restrict__ B,
                                               float* __restrict__ C, int M) {
  __shared__ float As[BK][BM];
  __shared__ float Bs[BK][BN];
  const int tid = threadIdx.x;
  const int row0 = blockIdx.x * BM;
  const int col0 = blockIdx.y * BN;
  const int ty = tid >> 4;   // 0..15
  const int tx = tid & 15;   // 0..15
  float acc[4][4] = {};
  for (int k0 = 0; k0 < DIM; k0 += BK) {
    // A tile: 64 rows x 16 k  (coalesced in k within 16-lane groups)
    {
      const int kk = tid & 15;
      const int rbase = tid >> 4;
#pragma unroll
      for (int i = 0; i < 4; ++i) {
        int r = rbase + i * 16;
        int row = row0 + r;
        As[kk][r] = (row < M) ? A[row * DIM + k0 + kk] : 0.f;
      }
    }
    // B tile: 16 k x 64 cols (coalesced in c)
    {
      const int c = tid & 63;
      const int kb = tid >> 6;  // 0..3
#pragma unroll
      for (int i = 0; i < 4; ++i) {
        int kk = kb + i * 4;
        Bs[kk][c] = B[(k0 + kk) * DIM + col0 + c];
      }
    }
    __syncthreads();
#pragma unroll
    for (int kk = 0; kk < BK; ++kk) {
      float4 a4 = *(const float4*)&As[kk][ty * 4];
      float4 b4 = *(const float4*)&Bs[kk][tx * 4];
      float av[4] = {a4.x, a4.y, a4.z, a4.w};
      float bv[4] = {b4.x, b4.y, b4.z, b4.w};
#pragma unroll
      for (int i = 0; i < 4; ++i)
#pragma unroll
        for (int j = 0; j < 4; ++j) acc[i][j] += av[i] * bv[j];
    }
    __syncthreads();
  }
#pragma unroll
  for (int i = 0; i < 4; ++i) {
    int row = row0 + ty * 4 + i;
    if (row < M) {
      float4 v = make_float4(acc[i][0], acc[i][1], acc[i][2], acc[i][3]);
      *(float4*)&C[row * DIM + col0 + tx * 4] = v;
    }
  }
}

// ---------------- per-node attention logits: al[n,h] = sum_o h[n,h,o]*a[h,o] ----------------
// one 64-lane wave per node; lane reads 4 contiguous floats; head = lane>>4
__global__ __launch_bounds__(256) void attn_logits(const float* __restrict__ h,
                                                   const float* __restrict__ a_src,
                                                   const float* __restrict__ a_dst,
                                                   float* __restrict__ al_s,
                                                   float* __restrict__ al_d) {
  int gid = blockIdx.x * blockDim.x + threadIdx.x;
  int node = gid >> 6;
  int lane = threadIdx.x & 63;
  if (node >= N_NODES) return;
  float4 hv = *(const float4*)&h[(size_t)node * DIM + lane * 4];
  float4 as = *(const float4*)&a_src[lane * 4];
  float4 ad = *(const float4*)&a_dst[lane * 4];
  float s = hv.x * as.x + hv.y * as.y + hv.z * as.z + hv.w * as.w;
  float d = hv.x * ad.x + hv.y * ad.y + hv.z * ad.z + hv.w * ad.w;
#pragma unroll
  for (int off = 8; off >= 1; off >>= 1) {
    s += __shfl_xor(s, off, 64);
    d += __shfl_xor(d, off, 64);
  }
  if ((lane & 15) == 0) {
    int head = lane >> 4;
    al_s[node * HEADS + head] = s;
    al_d[node * HEADS + head] = d;
  }
}

// ---------------- edge aggregation (no max-subtraction: exp(e) directly) ----------------
// one 64-lane wave per edge; lane covers 4 contiguous floats of the 256-wide row.
__global__ __launch_bounds__(256) void edge_agg(const int* __restrict__ src,
                                                const int* __restrict__ dst,
                                                const float* __restrict__ h,
                                                const float* __restrict__ al_s,
                                                const float* __restrict__ al_d,
                                                float* __restrict__ outb,
                                                float* __restrict__ denom) {
  long long gid = (long long)blockIdx.x * blockDim.x + threadIdx.x;
  int e = (int)(gid >> 6);
  if (e >= E_EDGES) return;
  int lane = threadIdx.x & 63;
  int s = src[e];
  int d = dst[e];
  int head = lane >> 4;
  float el = al_s[s * HEADS + head] + al_d[d * HEADS + head];
  el = el > 0.f ? el : NEG_SLOPE * el;
  float p = __expf(el);
  if ((lane & 15) == 0) atomicAdd(&denom[d * HEADS + head], p);
  float4 hv = *(const float4*)&h[(size_t)s * DIM + lane * 4];
  float* ob = &outb[(size_t)d * DIM + lane * 4];
  atomicAdd(ob + 0, p * hv.x);
  atomicAdd(ob + 1, p * hv.y);
  atomicAdd(ob + 2, p * hv.z);
  atomicAdd(ob + 3, p * hv.w);
}

// ---------------- layer-1 finalize: add self-loop, divide, +bias, ELU (in place on outb) ----------------
__global__ __launch_bounds__(256) void finalize1(const float* __restrict__ h,
                                                 const float* __restrict__ al_s,
                                                 const float* __restrict__ al_d,
                                                 const float* __restrict__ denom,
                                                 const float* __restrict__ bias,
                                                 float* __restrict__ outb) {
  int gid = blockIdx.x * blockDim.x + threadIdx.x;
  int node = gid >> 6;
  int lane = threadIdx.x & 63;
  if (node >= N_NODES) return;
  int head = lane >> 4;
  float el = al_s[node * HEADS + head] + al_d[node * HEADS + head];
  el = el > 0.f ? el : NEG_SLOPE * el;
  float p = __expf(el);
  float inv = 1.f / (denom[node * HEADS + head] + p);
  float4 hv = *(const float4*)&h[(size_t)node * DIM + lane * 4];
  float4 ov = *(const float4*)&outb[(size_t)node * DIM + lane * 4];
  float4 bv = *(const float4*)&bias[lane * 4];
  float r[4];
  r[0] = (ov.x + p * hv.x) * inv + bv.x;
  r[1] = (ov.y + p * hv.y) * inv + bv.y;
  r[2] = (ov.z + p * hv.z) * inv + bv.z;
  r[3] = (ov.w + p * hv.w) * inv + bv.w;
#pragma unroll
  for (int i = 0; i < 4; ++i) r[i] = r[i] > 0.f ? r[i] : expm1f(r[i]);  // ELU
  *(float4*)&outb[(size_t)node * DIM + lane * 4] = make_float4(r[0], r[1], r[2], r[3]);
}

// ---------------- layer-2 finalize: self-loop, divide, mean over heads, +b2 -> z (N x 64) ----------------
__global__ __launch_bounds__(256) void finalize2(const float* __restrict__ h2,
                                                 const float* __restrict__ aggb,
                                                 const float* __restrict__ al_s,
                                                 const float* __restrict__ al_d,
                                                 const float* __restrict__ denom,
                                                 const float* __restrict__ b2,
                                                 float* __restrict__ z) {
  int gid = blockIdx.x * blockDim.x + threadIdx.x;
  int node = gid >> 6;
  int lane = threadIdx.x & 63;  // latent dim index o
  if (node >= N_NODES) return;
  float acc = 0.f;
#pragma unroll
  for (int head = 0; head < HEADS; ++head) {
    float el = al_s[node * HEADS + head] + al_d[node * HEADS + head];
    el = el > 0.f ? el : NEG_SLOPE * el;
    float p = __expf(el);
    float inv = 1.f / (denom[node * HEADS + head] + p);
    size_t idx = (size_t)node * DIM + head * HO + lane;
    acc += (aggb[idx] + p * h2[idx]) * inv;
  }
  z[(size_t)node * HO + lane] = acc * 0.25f + b2[lane];
}

// ---------------- decoder: logits[e] = dot(z[src[e]], z[dst[e]]), 16 lanes per edge ----------------
__global__ __launch_bounds__(256) void decoder(const int* __restrict__ src,
                                               const int* __restrict__ dst,
                                               const float* __restrict__ z,
                                               float* __restrict__ out) {
  long long gid = (long long)blockIdx.x * blockDim.x + threadIdx.x;
  int e = (int)(gid >> 4);
  if (e >= E_EDGES) return;
  int l = threadIdx.x & 15;
  int s = src[e];
  int d = dst[e];
  float4 a = *(const float4*)&z[(size_t)s * HO + l * 4];
  float4 b = *(const float4*)&z[(size_t)d * HO + l * 4];
  float v = a.x * b.x + a.y * b.y + a.z * b.z + a.w * b.w;
#pragma unroll
  for (int off = 8; off >= 1; off >>= 1) v += __shfl_xor(v, off, 64);
  if (l == 0) out[e] = v;
}

extern "C" void kernel_launch(void* const* d_in, const int* in_sizes, int n_in,
                              void* d_out, int out_size, void* d_ws, size_t ws_size,
                              hipStream_t stream) {
  const float* x      = (const float*)d_in[0];
  const int*   ei     = (const int*)d_in[1];
  const float* W1     = (const float*)d_in[2];
  const float* a_src1 = (const float*)d_in[3];
  const float* a_dst1 = (const float*)d_in[4];
  const float* b1     = (const float*)d_in[5];
  const float* W2     = (const float*)d_in[6];
  const float* a_src2 = (const float*)d_in[7];
  const float* a_dst2 = (const float*)d_in[8];
  const float* b2     = (const float*)d_in[9];
  const int* src = ei;
  const int* dst = ei + E_EDGES;
  float* logits = (float*)d_out;

  float* bufA = (float*)d_ws;                          // N*256 (h1, then h2)
  float* bufB = bufA + (size_t)N_NODES * DIM;          // N*256 (agg1/ELU-out/x2, then agg2)
  float* zlat = bufB + (size_t)N_NODES * DIM;          // N*64
  float* als1 = zlat + (size_t)N_NODES * HO;
  float* ald1 = als1 + N_NODES * HEADS;
  float* den1 = ald1 + N_NODES * HEADS;
  float* als2 = den1 + N_NODES * HEADS;
  float* ald2 = als2 + N_NODES * HEADS;
  float* den2 = ald2 + N_NODES * HEADS;

  dim3 gemmGrid((N_NODES + BM - 1) / BM, DIM / BN);
  dim3 blk(256);
  int nodeBlocks = (N_NODES * 64 + 255) / 256;   // wave per node
  int edgeBlocks = (int)(((long long)E_EDGES * 64 + 255) / 256);  // wave per edge
  int decBlocks  = (int)(((long long)E_EDGES * 16 + 255) / 256);  // 16 lanes per edge

  // ---- layer 1 ----
  hipLaunchKernelGGL(gemm256, gemmGrid, blk, 0, stream, x, W1, bufA, N_NODES);
  hipLaunchKernelGGL(attn_logits, dim3(nodeBlocks), blk, 0, stream, bufA, a_src1, a_dst1, als1, ald1);
  hipMemsetAsync(bufB, 0, (size_t)N_NODES * DIM * sizeof(float), stream);
  hipMemsetAsync(den1, 0, (size_t)N_NODES * HEADS * sizeof(float), stream);
  hipLaunchKernelGGL(edge_agg, dim3(edgeBlocks), blk, 0, stream, src, dst, bufA, als1, ald1, bufB, den1);
  hipLaunchKernelGGL(finalize1, dim3(nodeBlocks), blk, 0, stream, bufA, als1, ald1, den1, b1, bufB);

  // ---- layer 2 ----
  hipLaunchKernelGGL(gemm256, gemmGrid, blk, 0, stream, bufB, W2, bufA, N_NODES);
  hipLaunchKernelGGL(attn_logits, dim3(nodeBlocks), blk, 0, stream, bufA, a_src2, a_dst2, als2, ald2);
  hipMemsetAsync(bufB, 0, (size_t)N_NODES * DIM * sizeof(float), stream);
  hipMemsetAsync(den2, 0, (size_t)N_NODES * HEADS * sizeof(float), stream);
  hipLaunchKernelGGL(edge_agg, dim3(edgeBlocks), blk, 0, stream, src, dst, bufA, als2, ald2, bufB, den2);
  hipLaunchKernelGGL(finalize2, dim3(nodeBlocks), blk, 0, stream, bufA, bufB, als2, ald2, den2, b2, zlat);

  // ---- decoder ----
  hipLaunchKernelGGL(decoder, dim3(decBlocks), blk, 0, stream, src, dst, zlat, logits);
}

// Round 2
// 654.098 us; speedup vs baseline: 8.8103x; 8.8103x over previous
//
#include <hip/hip_runtime.h>
#include <math.h>

#define N_NODES 50000
#define E_EDGES 800000
#define DIM 256      // IN_DIM = HID = 256 (= H*O for both layers)
#define HEADS 4
#define HO 64        // per-head output width (O1 = LAT = 64)
#define NEG_SLOPE 0.2f
#define SCAN_NBLK ((N_NODES + 255) / 256)   // 196

// ---------------- GEMM: C = A(M x 256) @ B(256 x 256), row-major ----------------
#define BM 64
#define BN 64
#define BK 16

__global__ __launch_bounds__(256) void gemm256(const float* __restrict__ A,
                                               const float* __restrict__ B,
                                               float* __restrict__ C, int M) {
  __shared__ float As[BK][BM];
  __shared__ float Bs[BK][BN];
  const int tid = threadIdx.x;
  const int row0 = blockIdx.x * BM;
  const int col0 = blockIdx.y * BN;
  const int ty = tid >> 4;   // 0..15
  const int tx = tid & 15;   // 0..15
  float acc[4][4] = {};
  for (int k0 = 0; k0 < DIM; k0 += BK) {
    {
      const int kk = tid & 15;
      const int rbase = tid >> 4;
#pragma unroll
      for (int i = 0; i < 4; ++i) {
        int r = rbase + i * 16;
        int row = row0 + r;
        As[kk][r] = (row < M) ? A[row * DIM + k0 + kk] : 0.f;
      }
    }
    {
      const int c = tid & 63;
      const int kb = tid >> 6;  // 0..3
#pragma unroll
      for (int i = 0; i < 4; ++i) {
        int kk = kb + i * 4;
        Bs[kk][c] = B[(k0 + kk) * DIM + col0 + c];
      }
    }
    __syncthreads();
#pragma unroll
    for (int kk = 0; kk < BK; ++kk) {
      float4 a4 = *(const float4*)&As[kk][ty * 4];
      float4 b4 = *(const float4*)&Bs[kk][tx * 4];
      float av[4] = {a4.x, a4.y, a4.z, a4.w};
      float bv[4] = {b4.x, b4.y, b4.z, b4.w};
#pragma unroll
      for (int i = 0; i < 4; ++i)
#pragma unroll
        for (int j = 0; j < 4; ++j) acc[i][j] += av[i] * bv[j];
    }
    __syncthreads();
  }
#pragma unroll
  for (int i = 0; i < 4; ++i) {
    int row = row0 + ty * 4 + i;
    if (row < M) {
      float4 v = make_float4(acc[i][0], acc[i][1], acc[i][2], acc[i][3]);
      *(float4*)&C[row * DIM + col0 + tx * 4] = v;
    }
  }
}

// ---------------- per-node attention logits ----------------
__global__ __launch_bounds__(256) void attn_logits(const float* __restrict__ h,
                                                   const float* __restrict__ a_src,
                                                   const float* __restrict__ a_dst,
                                                   float* __restrict__ al_s,
                                                   float* __restrict__ al_d) {
  int gid = blockIdx.x * blockDim.x + threadIdx.x;
  int node = gid >> 6;
  int lane = threadIdx.x & 63;
  if (node >= N_NODES) return;
  float4 hv = *(const float4*)&h[(size_t)node * DIM + lane * 4];
  float4 as = *(const float4*)&a_src[lane * 4];
  float4 ad = *(const float4*)&a_dst[lane * 4];
  float s = hv.x * as.x + hv.y * as.y + hv.z * as.z + hv.w * as.w;
  float d = hv.x * ad.x + hv.y * ad.y + hv.z * ad.z + hv.w * ad.w;
#pragma unroll
  for (int off = 8; off >= 1; off >>= 1) {
    s += __shfl_xor(s, off, 64);
    d += __shfl_xor(d, off, 64);
  }
  if ((lane & 15) == 0) {
    int head = lane >> 4;
    al_s[node * HEADS + head] = s;
    al_d[node * HEADS + head] = d;
  }
}

// ---------------- CSR build ----------------
__global__ __launch_bounds__(256) void histo(const int* __restrict__ dst, int* __restrict__ deg) {
  int e = blockIdx.x * blockDim.x + threadIdx.x;
  if (e < E_EDGES) atomicAdd(&deg[dst[e]], 1);
}

__global__ __launch_bounds__(256) void scan1(const int* __restrict__ deg,
                                             int* __restrict__ excl,
                                             int* __restrict__ blockSums) {
  __shared__ int tmp[256];
  int i = blockIdx.x * 256 + threadIdx.x;
  int v = (i < N_NODES) ? deg[i] : 0;
  tmp[threadIdx.x] = v;
  __syncthreads();
  for (int off = 1; off < 256; off <<= 1) {
    int t = (threadIdx.x >= off) ? tmp[threadIdx.x - off] : 0;
    __syncthreads();
    tmp[threadIdx.x] += t;
    __syncthreads();
  }
  int incl = tmp[threadIdx.x];
  if (i < N_NODES) excl[i] = incl - v;
  if (threadIdx.x == 255) blockSums[blockIdx.x] = incl;
}

__global__ __launch_bounds__(256) void scan2(int* __restrict__ blockSums) {
  __shared__ int tmp[256];
  int i = threadIdx.x;
  int v = (i < SCAN_NBLK) ? blockSums[i] : 0;
  tmp[i] = v;
  __syncthreads();
  for (int off = 1; off < 256; off <<= 1) {
    int t = (i >= off) ? tmp[i - off] : 0;
    __syncthreads();
    tmp[i] += t;
    __syncthreads();
  }
  if (i < SCAN_NBLK) blockSums[i] = tmp[i] - v;  // exclusive
}

__global__ __launch_bounds__(256) void scan3(int* __restrict__ excl,
                                             const int* __restrict__ blockSums,
                                             int* __restrict__ cursor) {
  int i = blockIdx.x * 256 + threadIdx.x;
  if (i < N_NODES) {
    int r = excl[i] + blockSums[blockIdx.x];
    excl[i] = r;
    cursor[i] = r;
  }
}

__global__ __launch_bounds__(256) void scatter(const int* __restrict__ src,
                                               const int* __restrict__ dst,
                                               int* __restrict__ cursor,
                                               int* __restrict__ csr_src) {
  int e = blockIdx.x * blockDim.x + threadIdx.x;
  if (e >= E_EDGES) return;
  int pos = atomicAdd(&cursor[dst[e]], 1);
  csr_src[pos] = src[e];
}

// ---------------- layer-1 aggregate + finalize (gather over CSR, no atomics) ----------------
__global__ __launch_bounds__(256) void agg1(const int* __restrict__ rowptr,
                                            const int* __restrict__ csr_src,
                                            const float* __restrict__ h,
                                            const float* __restrict__ als,
                                            const float* __restrict__ ald,
                                            const float* __restrict__ bias,
                                            float* __restrict__ out) {
  int gid = blockIdx.x * blockDim.x + threadIdx.x;
  int node = gid >> 6;
  if (node >= N_NODES) return;
  int lane = threadIdx.x & 63;
  int head = lane >> 4;
  int rs = rowptr[node];
  int re = (node < N_NODES - 1) ? rowptr[node + 1] : E_EDGES;
  float aldv = ald[node * HEADS + head];
  float den = 0.f;
  float a0 = 0.f, a1 = 0.f, a2 = 0.f, a3 = 0.f;
  int e = rs;
  for (; e + 1 < re; e += 2) {
    int s0 = csr_src[e], s1 = csr_src[e + 1];
    float e0 = als[s0 * HEADS + head] + aldv;
    float e1 = als[s1 * HEADS + head] + aldv;
    float4 h0 = *(const float4*)&h[(size_t)s0 * DIM + lane * 4];
    float4 h1 = *(const float4*)&h[(size_t)s1 * DIM + lane * 4];
    e0 = e0 > 0.f ? e0 : NEG_SLOPE * e0;
    e1 = e1 > 0.f ? e1 : NEG_SLOPE * e1;
    float p0 = __expf(e0), p1 = __expf(e1);
    den += p0 + p1;
    a0 += p0 * h0.x + p1 * h1.x;
    a1 += p0 * h0.y + p1 * h1.y;
    a2 += p0 * h0.z + p1 * h1.z;
    a3 += p0 * h0.w + p1 * h1.w;
  }
  if (e < re) {
    int s0 = csr_src[e];
    float e0 = als[s0 * HEADS + head] + aldv;
    float4 h0 = *(const float4*)&h[(size_t)s0 * DIM + lane * 4];
    e0 = e0 > 0.f ? e0 : NEG_SLOPE * e0;
    float p0 = __expf(e0);
    den += p0;
    a0 += p0 * h0.x; a1 += p0 * h0.y; a2 += p0 * h0.z; a3 += p0 * h0.w;
  }
  // self loop
  {
    float es = als[node * HEADS + head] + aldv;
    es = es > 0.f ? es : NEG_SLOPE * es;
    float ps = __expf(es);
    float4 hs = *(const float4*)&h[(size_t)node * DIM + lane * 4];
    den += ps;
    a0 += ps * hs.x; a1 += ps * hs.y; a2 += ps * hs.z; a3 += ps * hs.w;
  }
  float inv = 1.f / den;
  float4 bv = *(const float4*)&bias[lane * 4];
  float r0 = a0 * inv + bv.x;
  float r1 = a1 * inv + bv.y;
  float r2 = a2 * inv + bv.z;
  float r3 = a3 * inv + bv.w;
  r0 = r0 > 0.f ? r0 : expm1f(r0);
  r1 = r1 > 0.f ? r1 : expm1f(r1);
  r2 = r2 > 0.f ? r2 : expm1f(r2);
  r3 = r3 > 0.f ? r3 : expm1f(r3);
  *(float4*)&out[(size_t)node * DIM + lane * 4] = make_float4(r0, r1, r2, r3);
}

// ---------------- layer-2 aggregate + finalize (mean over heads -> z N x 64) ----------------
__global__ __launch_bounds__(256) void agg2(const int* __restrict__ rowptr,
                                            const int* __restrict__ csr_src,
                                            const float* __restrict__ h,
                                            const float* __restrict__ als,
                                            const float* __restrict__ ald,
                                            const float* __restrict__ b2,
                                            float* __restrict__ z) {
  int gid = blockIdx.x * blockDim.x + threadIdx.x;
  int node = gid >> 6;
  if (node >= N_NODES) return;
  int lane = threadIdx.x & 63;
  int head = lane >> 4;
  int rs = rowptr[node];
  int re = (node < N_NODES - 1) ? rowptr[node + 1] : E_EDGES;
  float aldv = ald[node * HEADS + head];
  float den = 0.f;
  float a0 = 0.f, a1 = 0.f, a2 = 0.f, a3 = 0.f;
  int e = rs;
  for (; e + 1 < re; e += 2) {
    int s0 = csr_src[e], s1 = csr_src[e + 1];
    float e0 = als[s0 * HEADS + head] + aldv;
    float e1 = als[s1 * HEADS + head] + aldv;
    float4 h0 = *(const float4*)&h[(size_t)s0 * DIM + lane * 4];
    float4 h1 = *(const float4*)&h[(size_t)s1 * DIM + lane * 4];
    e0 = e0 > 0.f ? e0 : NEG_SLOPE * e0;
    e1 = e1 > 0.f ? e1 : NEG_SLOPE * e1;
    float p0 = __expf(e0), p1 = __expf(e1);
    den += p0 + p1;
    a0 += p0 * h0.x + p1 * h1.x;
    a1 += p0 * h0.y + p1 * h1.y;
    a2 += p0 * h0.z + p1 * h1.z;
    a3 += p0 * h0.w + p1 * h1.w;
  }
  if (e < re) {
    int s0 = csr_src[e];
    float e0 = als[s0 * HEADS + head] + aldv;
    float4 h0 = *(const float4*)&h[(size_t)s0 * DIM + lane * 4];
    e0 = e0 > 0.f ? e0 : NEG_SLOPE * e0;
    float p0 = __expf(e0);
    den += p0;
    a0 += p0 * h0.x; a1 += p0 * h0.y; a2 += p0 * h0.z; a3 += p0 * h0.w;
  }
  {
    float es = als[node * HEADS + head] + aldv;
    es = es > 0.f ? es : NEG_SLOPE * es;
    float ps = __expf(es);
    float4 hs = *(const float4*)&h[(size_t)node * DIM + lane * 4];
    den += ps;
    a0 += ps * hs.x; a1 += ps * hs.y; a2 += ps * hs.z; a3 += ps * hs.w;
  }
  float inv = 1.f / den;
  float r0 = a0 * inv, r1 = a1 * inv, r2 = a2 * inv, r3 = a3 * inv;
  // mean over heads: heads live at lane ^ 16, lane ^ 32
  r0 += __shfl_xor(r0, 16, 64); r0 += __shfl_xor(r0, 32, 64);
  r1 += __shfl_xor(r1, 16, 64); r1 += __shfl_xor(r1, 32, 64);
  r2 += __shfl_xor(r2, 16, 64); r2 += __shfl_xor(r2, 32, 64);
  r3 += __shfl_xor(r3, 16, 64); r3 += __shfl_xor(r3, 32, 64);
  if (lane < 16) {
    float4 bv = *(const float4*)&b2[lane * 4];
    float4 v = make_float4(r0 * 0.25f + bv.x, r1 * 0.25f + bv.y,
                           r2 * 0.25f + bv.z, r3 * 0.25f + bv.w);
    *(float4*)&z[(size_t)node * HO + lane * 4] = v;
  }
}

// ---------------- decoder ----------------
__global__ __launch_bounds__(256) void decoder(const int* __restrict__ src,
                                               const int* __restrict__ dst,
                                               const float* __restrict__ z,
                                               float* __restrict__ out) {
  long long gid = (long long)blockIdx.x * blockDim.x + threadIdx.x;
  int e = (int)(gid >> 4);
  if (e >= E_EDGES) return;
  int l = threadIdx.x & 15;
  int s = src[e];
  int d = dst[e];
  float4 a = *(const float4*)&z[(size_t)s * HO + l * 4];
  float4 b = *(const float4*)&z[(size_t)d * HO + l * 4];
  float v = a.x * b.x + a.y * b.y + a.z * b.z + a.w * b.w;
#pragma unroll
  for (int off = 8; off >= 1; off >>= 1) v += __shfl_xor(v, off, 64);
  if (l == 0) out[e] = v;
}

extern "C" void kernel_launch(void* const* d_in, const int* in_sizes, int n_in,
                              void* d_out, int out_size, void* d_ws, size_t ws_size,
                              hipStream_t stream) {
  const float* x      = (const float*)d_in[0];
  const int*   ei     = (const int*)d_in[1];
  const float* W1     = (const float*)d_in[2];
  const float* a_src1 = (const float*)d_in[3];
  const float* a_dst1 = (const float*)d_in[4];
  const float* b1     = (const float*)d_in[5];
  const float* W2     = (const float*)d_in[6];
  const float* a_src2 = (const float*)d_in[7];
  const float* a_dst2 = (const float*)d_in[8];
  const float* b2     = (const float*)d_in[9];
  const int* src = ei;
  const int* dst = ei + E_EDGES;
  float* logits = (float*)d_out;

  float* bufA = (float*)d_ws;                          // N*256 (h1, then h2)
  float* bufB = bufA + (size_t)N_NODES * DIM;          // N*256 (elu(gat1) = x2)
  float* zlat = bufB + (size_t)N_NODES * DIM;          // N*64
  float* als1 = zlat + (size_t)N_NODES * HO;
  float* ald1 = als1 + N_NODES * HEADS;
  float* als2 = ald1 + N_NODES * HEADS;
  float* ald2 = als2 + N_NODES * HEADS;
  int* deg      = (int*)(ald2 + N_NODES * HEADS);
  int* rowptr   = deg + N_NODES;
  int* cursor   = rowptr + N_NODES;
  int* blockSums= cursor + N_NODES;
  int* csr_src  = blockSums + 256;

  dim3 gemmGrid((N_NODES + BM - 1) / BM, DIM / BN);
  dim3 blk(256);
  int nodeBlocks = (N_NODES * 64 + 255) / 256;
  int edgeThreadBlocks = (E_EDGES + 255) / 256;
  int decBlocks  = (int)(((long long)E_EDGES * 16 + 255) / 256);

  // ---- CSR build (graph is the same for both layers) ----
  hipMemsetAsync(deg, 0, N_NODES * sizeof(int), stream);
  hipLaunchKernelGGL(histo, dim3(edgeThreadBlocks), blk, 0, stream, dst, deg);
  hipLaunchKernelGGL(scan1, dim3(SCAN_NBLK), blk, 0, stream, deg, rowptr, blockSums);
  hipLaunchKernelGGL(scan2, dim3(1), blk, 0, stream, blockSums);
  hipLaunchKernelGGL(scan3, dim3(SCAN_NBLK), blk, 0, stream, rowptr, blockSums, cursor);
  hipLaunchKernelGGL(scatter, dim3(edgeThreadBlocks), blk, 0, stream, src, dst, cursor, csr_src);

  // ---- layer 1 ----
  hipLaunchKernelGGL(gemm256, gemmGrid, blk, 0, stream, x, W1, bufA, N_NODES);
  hipLaunchKernelGGL(attn_logits, dim3(nodeBlocks), blk, 0, stream, bufA, a_src1, a_dst1, als1, ald1);
  hipLaunchKernelGGL(agg1, dim3(nodeBlocks), blk, 0, stream, rowptr, csr_src, bufA, als1, ald1, b1, bufB);

  // ---- layer 2 ----
  hipLaunchKernelGGL(gemm256, gemmGrid, blk, 0, stream, bufB, W2, bufA, N_NODES);
  hipLaunchKernelGGL(attn_logits, dim3(nodeBlocks), blk, 0, stream, bufA, a_src2, a_dst2, als2, ald2);
  hipLaunchKernelGGL(agg2, dim3(nodeBlocks), blk, 0, stream, rowptr, csr_src, bufA, als2, ald2, b2, zlat);

  // ---- decoder ----
  hipLaunchKernelGGL(decoder, dim3(decBlocks), blk, 0, stream, src, dst, zlat, logits);
}

// Round 3
// 505.497 us; speedup vs baseline: 11.4003x; 1.2940x over previous
//
#include <hip/hip_runtime.h>
#include <math.h>

#define N_NODES 50000
#define E_EDGES 800000
#define DIM 256      // IN_DIM = HID = 256 (= H*O for both layers)
#define HEADS 4
#define HO 64        // per-head output width (O1 = LAT = 64)
#define NEG_SLOPE 0.2f
#define SCAN_NBLK ((N_NODES + 255) / 256)   // 196

typedef __attribute__((ext_vector_type(8))) short bf16x8;
typedef __attribute__((ext_vector_type(4))) float f32x4;

static __device__ inline ushort f2bf(float f) {
  union { float f; unsigned u; } v; v.f = f;
  unsigned r = (v.u + 0x7fff + ((v.u >> 16) & 1)) >> 16;  // RTNE
  return (ushort)r;
}
static __device__ inline float bf2f(ushort h) {
  union { unsigned u; float f; } v; v.u = ((unsigned)h) << 16;
  return v.f;
}

// ---------------- split fp32 -> bf16 hi + bf16 lo ----------------
__global__ __launch_bounds__(256) void cvt_split(const float* __restrict__ in,
                                                 ushort* __restrict__ hi,
                                                 ushort* __restrict__ lo, int n4) {
  int i = blockIdx.x * 256 + threadIdx.x;
  if (i >= n4) return;
  float4 v = *(const float4*)&in[(size_t)i * 4];
  ushort4 h, l;
  h.x = f2bf(v.x); l.x = f2bf(v.x - bf2f(h.x));
  h.y = f2bf(v.y); l.y = f2bf(v.y - bf2f(h.y));
  h.z = f2bf(v.z); l.z = f2bf(v.z - bf2f(h.z));
  h.w = f2bf(v.w); l.w = f2bf(v.w - bf2f(h.w));
  *(ushort4*)&hi[(size_t)i * 4] = h;
  *(ushort4*)&lo[(size_t)i * 4] = l;
}

// W (256x256) -> BT (transposed) hi/lo
__global__ __launch_bounds__(256) void cvt_split_T(const float* __restrict__ W,
                                                   ushort* __restrict__ bthi,
                                                   ushort* __restrict__ btlo) {
  int idx = blockIdx.x * 256 + threadIdx.x;   // 65536 threads
  int k = idx >> 8, n = idx & 255;
  float v = W[idx];                            // W[k][n]
  ushort h = f2bf(v);
  ushort l = f2bf(v - bf2f(h));
  bthi[n * 256 + k] = h;
  btlo[n * 256 + k] = l;
}

// ---------------- split-bf16 MFMA GEMM: C(Mx256) = (Ahi+Alo) @ (Bhi+Blo) ----------------
// B supplied transposed: BT[n][k]. 128x128 tile, 4 waves, 16x16x32 MFMA, 3 passes.
#define GBM 128
#define GBK 32
#define LDK 40   // padded LDS k-stride (ushorts): 80B rows -> 16B aligned, 2-way banks max

__global__ __launch_bounds__(256) void gemm_mfma(const ushort* __restrict__ Ahi,
                                                 const ushort* __restrict__ Alo,
                                                 const ushort* __restrict__ Bhi,
                                                 const ushort* __restrict__ Blo,
                                                 float* __restrict__ C, int M) {
  __shared__ __align__(16) ushort As[2][GBM][LDK];
  __shared__ __align__(16) ushort Bs[2][GBM][LDK];
  const int tid = threadIdx.x;
  const int lane = tid & 63;
  const int wave = tid >> 6;
  const int row0 = blockIdx.x * GBM;
  const int col0 = blockIdx.y * GBM;
  const int wm = (wave & 1) * 64;
  const int wn = (wave >> 1) * 64;
  const int rA = lane & 15;
  const int kb = (lane >> 4) * 8;

  f32x4 acc[4][4] = {};

  for (int k0 = 0; k0 < DIM; k0 += GBK) {
    // stage tiles: 512 chunks of 8 ushorts per plane; thread does chunks tid, tid+256
#pragma unroll
    for (int qq = 0; qq < 2; ++qq) {
      int q = tid + qq * 256;
      int r = q >> 2, c = q & 3;
      int grow = row0 + r;
      bf16x8 vh = {}, vl = {};
      if (grow < M) {
        vh = *(const bf16x8*)&Ahi[(size_t)grow * DIM + k0 + c * 8];
        vl = *(const bf16x8*)&Alo[(size_t)grow * DIM + k0 + c * 8];
      }
      *(bf16x8*)&As[0][r][c * 8] = vh;
      *(bf16x8*)&As[1][r][c * 8] = vl;
      bf16x8 wh = *(const bf16x8*)&Bhi[(size_t)(col0 + r) * DIM + k0 + c * 8];
      bf16x8 wl = *(const bf16x8*)&Blo[(size_t)(col0 + r) * DIM + k0 + c * 8];
      *(bf16x8*)&Bs[0][r][c * 8] = wh;
      *(bf16x8*)&Bs[1][r][c * 8] = wl;
    }
    __syncthreads();

    bf16x8 af[2][4], bfr[2][4];
#pragma unroll
    for (int mi = 0; mi < 4; ++mi) {
      af[0][mi] = *(const bf16x8*)&As[0][wm + mi * 16 + rA][kb];
      af[1][mi] = *(const bf16x8*)&As[1][wm + mi * 16 + rA][kb];
    }
#pragma unroll
    for (int ni = 0; ni < 4; ++ni) {
      bfr[0][ni] = *(const bf16x8*)&Bs[0][wn + ni * 16 + rA][kb];
      bfr[1][ni] = *(const bf16x8*)&Bs[1][wn + ni * 16 + rA][kb];
    }
#pragma unroll
    for (int mi = 0; mi < 4; ++mi)
#pragma unroll
      for (int ni = 0; ni < 4; ++ni) {
        acc[mi][ni] = __builtin_amdgcn_mfma_f32_16x16x32_bf16(af[0][mi], bfr[0][ni], acc[mi][ni], 0, 0, 0);
        acc[mi][ni] = __builtin_amdgcn_mfma_f32_16x16x32_bf16(af[0][mi], bfr[1][ni], acc[mi][ni], 0, 0, 0);
        acc[mi][ni] = __builtin_amdgcn_mfma_f32_16x16x32_bf16(af[1][mi], bfr[0][ni], acc[mi][ni], 0, 0, 0);
      }
    __syncthreads();
  }

  // C/D layout: col = lane&15, row = (lane>>4)*4 + reg
#pragma unroll
  for (int mi = 0; mi < 4; ++mi) {
    int rbase = row0 + wm + mi * 16 + (lane >> 4) * 4;
#pragma unroll
    for (int ni = 0; ni < 4; ++ni) {
      int col = col0 + wn + ni * 16 + (lane & 15);
#pragma unroll
      for (int r = 0; r < 4; ++r) {
        int row = rbase + r;
        if (row < M) C[(size_t)row * DIM + col] = acc[mi][ni][r];
      }
    }
  }
}

// ---------------- per-node attention logits ----------------
__global__ __launch_bounds__(256) void attn_logits(const float* __restrict__ h,
                                                   const float* __restrict__ a_src,
                                                   const float* __restrict__ a_dst,
                                                   float* __restrict__ al_s,
                                                   float* __restrict__ al_d) {
  int gid = blockIdx.x * blockDim.x + threadIdx.x;
  int node = gid >> 6;
  int lane = threadIdx.x & 63;
  if (node >= N_NODES) return;
  float4 hv = *(const float4*)&h[(size_t)node * DIM + lane * 4];
  float4 as = *(const float4*)&a_src[lane * 4];
  float4 ad = *(const float4*)&a_dst[lane * 4];
  float s = hv.x * as.x + hv.y * as.y + hv.z * as.z + hv.w * as.w;
  float d = hv.x * ad.x + hv.y * ad.y + hv.z * ad.z + hv.w * ad.w;
#pragma unroll
  for (int off = 8; off >= 1; off >>= 1) {
    s += __shfl_xor(s, off, 64);
    d += __shfl_xor(d, off, 64);
  }
  if ((lane & 15) == 0) {
    int head = lane >> 4;
    al_s[node * HEADS + head] = s;
    al_d[node * HEADS + head] = d;
  }
}

// ---------------- CSR build ----------------
__global__ __launch_bounds__(256) void histo(const int* __restrict__ dst, int* __restrict__ deg) {
  int e = blockIdx.x * blockDim.x + threadIdx.x;
  if (e < E_EDGES) atomicAdd(&deg[dst[e]], 1);
}

__global__ __launch_bounds__(256) void scan1(const int* __restrict__ deg,
                                             int* __restrict__ excl,
                                             int* __restrict__ blockSums) {
  __shared__ int tmp[256];
  int i = blockIdx.x * 256 + threadIdx.x;
  int v = (i < N_NODES) ? deg[i] : 0;
  tmp[threadIdx.x] = v;
  __syncthreads();
  for (int off = 1; off < 256; off <<= 1) {
    int t = (threadIdx.x >= off) ? tmp[threadIdx.x - off] : 0;
    __syncthreads();
    tmp[threadIdx.x] += t;
    __syncthreads();
  }
  int incl = tmp[threadIdx.x];
  if (i < N_NODES) excl[i] = incl - v;
  if (threadIdx.x == 255) blockSums[blockIdx.x] = incl;
}

__global__ __launch_bounds__(256) void scan2(int* __restrict__ blockSums) {
  __shared__ int tmp[256];
  int i = threadIdx.x;
  int v = (i < SCAN_NBLK) ? blockSums[i] : 0;
  tmp[i] = v;
  __syncthreads();
  for (int off = 1; off < 256; off <<= 1) {
    int t = (i >= off) ? tmp[i - off] : 0;
    __syncthreads();
    tmp[i] += t;
    __syncthreads();
  }
  if (i < SCAN_NBLK) blockSums[i] = tmp[i] - v;  // exclusive
}

__global__ __launch_bounds__(256) void scan3(int* __restrict__ excl,
                                             const int* __restrict__ blockSums,
                                             int* __restrict__ cursor) {
  int i = blockIdx.x * 256 + threadIdx.x;
  if (i < N_NODES) {
    int r = excl[i] + blockSums[blockIdx.x];
    excl[i] = r;
    cursor[i] = r;
  }
}

__global__ __launch_bounds__(256) void scatter(const int* __restrict__ src,
                                               const int* __restrict__ dst,
                                               int* __restrict__ cursor,
                                               int* __restrict__ csr_src) {
  int e = blockIdx.x * blockDim.x + threadIdx.x;
  if (e >= E_EDGES) return;
  int pos = atomicAdd(&cursor[dst[e]], 1);
  csr_src[pos] = src[e];
}

// ---------------- layer-1 aggregate + finalize -> ELU output as bf16 hi/lo split ----------------
__global__ __launch_bounds__(256) void agg1(const int* __restrict__ rowptr,
                                            const int* __restrict__ csr_src,
                                            const float* __restrict__ h,
                                            const float* __restrict__ als,
                                            const float* __restrict__ ald,
                                            const float* __restrict__ bias,
                                            ushort* __restrict__ xhi,
                                            ushort* __restrict__ xlo) {
  int gid = blockIdx.x * blockDim.x + threadIdx.x;
  int node = gid >> 6;
  if (node >= N_NODES) return;
  int lane = threadIdx.x & 63;
  int head = lane >> 4;
  int rs = rowptr[node];
  int re = (node < N_NODES - 1) ? rowptr[node + 1] : E_EDGES;
  float aldv = ald[node * HEADS + head];
  float den = 0.f;
  float a0 = 0.f, a1 = 0.f, a2 = 0.f, a3 = 0.f;
  int e = rs;
  for (; e + 1 < re; e += 2) {
    int s0 = csr_src[e], s1 = csr_src[e + 1];
    float e0 = als[s0 * HEADS + head] + aldv;
    float e1 = als[s1 * HEADS + head] + aldv;
    float4 h0 = *(const float4*)&h[(size_t)s0 * DIM + lane * 4];
    float4 h1 = *(const float4*)&h[(size_t)s1 * DIM + lane * 4];
    e0 = e0 > 0.f ? e0 : NEG_SLOPE * e0;
    e1 = e1 > 0.f ? e1 : NEG_SLOPE * e1;
    float p0 = __expf(e0), p1 = __expf(e1);
    den += p0 + p1;
    a0 += p0 * h0.x + p1 * h1.x;
    a1 += p0 * h0.y + p1 * h1.y;
    a2 += p0 * h0.z + p1 * h1.z;
    a3 += p0 * h0.w + p1 * h1.w;
  }
  if (e < re) {
    int s0 = csr_src[e];
    float e0 = als[s0 * HEADS + head] + aldv;
    float4 h0 = *(const float4*)&h[(size_t)s0 * DIM + lane * 4];
    e0 = e0 > 0.f ? e0 : NEG_SLOPE * e0;
    float p0 = __expf(e0);
    den += p0;
    a0 += p0 * h0.x; a1 += p0 * h0.y; a2 += p0 * h0.z; a3 += p0 * h0.w;
  }
  // self loop
  {
    float es = als[node * HEADS + head] + aldv;
    es = es > 0.f ? es : NEG_SLOPE * es;
    float ps = __expf(es);
    float4 hs = *(const float4*)&h[(size_t)node * DIM + lane * 4];
    den += ps;
    a0 += ps * hs.x; a1 += ps * hs.y; a2 += ps * hs.z; a3 += ps * hs.w;
  }
  float inv = 1.f / den;
  float4 bv = *(const float4*)&bias[lane * 4];
  float r0 = a0 * inv + bv.x;
  float r1 = a1 * inv + bv.y;
  float r2 = a2 * inv + bv.z;
  float r3 = a3 * inv + bv.w;
  r0 = r0 > 0.f ? r0 : expm1f(r0);
  r1 = r1 > 0.f ? r1 : expm1f(r1);
  r2 = r2 > 0.f ? r2 : expm1f(r2);
  r3 = r3 > 0.f ? r3 : expm1f(r3);
  ushort4 oh, ol;
  oh.x = f2bf(r0); ol.x = f2bf(r0 - bf2f(oh.x));
  oh.y = f2bf(r1); ol.y = f2bf(r1 - bf2f(oh.y));
  oh.z = f2bf(r2); ol.z = f2bf(r2 - bf2f(oh.z));
  oh.w = f2bf(r3); ol.w = f2bf(r3 - bf2f(oh.w));
  *(ushort4*)&xhi[(size_t)node * DIM + lane * 4] = oh;
  *(ushort4*)&xlo[(size_t)node * DIM + lane * 4] = ol;
}

// ---------------- layer-2 aggregate + finalize (mean over heads -> z N x 64) ----------------
__global__ __launch_bounds__(256) void agg2(const int* __restrict__ rowptr,
                                            const int* __restrict__ csr_src,
                                            const float* __restrict__ h,
                                            const float* __restrict__ als,
                                            const float* __restrict__ ald,
                                            const float* __restrict__ b2,
                                            float* __restrict__ z) {
  int gid = blockIdx.x * blockDim.x + threadIdx.x;
  int node = gid >> 6;
  if (node >= N_NODES) return;
  int lane = threadIdx.x & 63;
  int head = lane >> 4;
  int rs = rowptr[node];
  int re = (node < N_NODES - 1) ? rowptr[node + 1] : E_EDGES;
  float aldv = ald[node * HEADS + head];
  float den = 0.f;
  float a0 = 0.f, a1 = 0.f, a2 = 0.f, a3 = 0.f;
  int e = rs;
  for (; e + 1 < re; e += 2) {
    int s0 = csr_src[e], s1 = csr_src[e + 1];
    float e0 = als[s0 * HEADS + head] + aldv;
    float e1 = als[s1 * HEADS + head] + aldv;
    float4 h0 = *(const float4*)&h[(size_t)s0 * DIM + lane * 4];
    float4 h1 = *(const float4*)&h[(size_t)s1 * DIM + lane * 4];
    e0 = e0 > 0.f ? e0 : NEG_SLOPE * e0;
    e1 = e1 > 0.f ? e1 : NEG_SLOPE * e1;
    float p0 = __expf(e0), p1 = __expf(e1);
    den += p0 + p1;
    a0 += p0 * h0.x + p1 * h1.x;
    a1 += p0 * h0.y + p1 * h1.y;
    a2 += p0 * h0.z + p1 * h1.z;
    a3 += p0 * h0.w + p1 * h1.w;
  }
  if (e < re) {
    int s0 = csr_src[e];
    float e0 = als[s0 * HEADS + head] + aldv;
    float4 h0 = *(const float4*)&h[(size_t)s0 * DIM + lane * 4];
    e0 = e0 > 0.f ? e0 : NEG_SLOPE * e0;
    float p0 = __expf(e0);
    den += p0;
    a0 += p0 * h0.x; a1 += p0 * h0.y; a2 += p0 * h0.z; a3 += p0 * h0.w;
  }
  {
    float es = als[node * HEADS + head] + aldv;
    es = es > 0.f ? es : NEG_SLOPE * es;
    float ps = __expf(es);
    float4 hs = *(const float4*)&h[(size_t)node * DIM + lane * 4];
    den += ps;
    a0 += ps * hs.x; a1 += ps * hs.y; a2 += ps * hs.z; a3 += ps * hs.w;
  }
  float inv = 1.f / den;
  float r0 = a0 * inv, r1 = a1 * inv, r2 = a2 * inv, r3 = a3 * inv;
  r0 += __shfl_xor(r0, 16, 64); r0 += __shfl_xor(r0, 32, 64);
  r1 += __shfl_xor(r1, 16, 64); r1 += __shfl_xor(r1, 32, 64);
  r2 += __shfl_xor(r2, 16, 64); r2 += __shfl_xor(r2, 32, 64);
  r3 += __shfl_xor(r3, 16, 64); r3 += __shfl_xor(r3, 32, 64);
  if (lane < 16) {
    float4 bv = *(const float4*)&b2[lane * 4];
    float4 v = make_float4(r0 * 0.25f + bv.x, r1 * 0.25f + bv.y,
                           r2 * 0.25f + bv.z, r3 * 0.25f + bv.w);
    *(float4*)&z[(size_t)node * HO + lane * 4] = v;
  }
}

// ---------------- decoder ----------------
__global__ __launch_bounds__(256) void decoder(const int* __restrict__ src,
                                               const int* __restrict__ dst,
                                               const float* __restrict__ z,
                                               float* __restrict__ out) {
  long long gid = (long long)blockIdx.x * blockDim.x + threadIdx.x;
  int e = (int)(gid >> 4);
  if (e >= E_EDGES) return;
  int l = threadIdx.x & 15;
  int s = src[e];
  int d = dst[e];
  float4 a = *(const float4*)&z[(size_t)s * HO + l * 4];
  float4 b = *(const float4*)&z[(size_t)d * HO + l * 4];
  float v = a.x * b.x + a.y * b.y + a.z * b.z + a.w * b.w;
#pragma unroll
  for (int off = 8; off >= 1; off >>= 1) v += __shfl_xor(v, off, 64);
  if (l == 0) out[e] = v;
}

extern "C" void kernel_launch(void* const* d_in, const int* in_sizes, int n_in,
                              void* d_out, int out_size, void* d_ws, size_t ws_size,
                              hipStream_t stream) {
  const float* x      = (const float*)d_in[0];
  const int*   ei     = (const int*)d_in[1];
  const float* W1     = (const float*)d_in[2];
  const float* a_src1 = (const float*)d_in[3];
  const float* a_dst1 = (const float*)d_in[4];
  const float* b1     = (const float*)d_in[5];
  const float* W2     = (const float*)d_in[6];
  const float* a_src2 = (const float*)d_in[7];
  const float* a_dst2 = (const float*)d_in[8];
  const float* b2     = (const float*)d_in[9];
  const int* src = ei;
  const int* dst = ei + E_EDGES;
  float* logits = (float*)d_out;

  float* bufA = (float*)d_ws;                          // N*256 fp32 (h1, then h2)
  float* zlat = bufA + (size_t)N_NODES * DIM;          // N*64
  float* als1 = zlat + (size_t)N_NODES * HO;
  float* ald1 = als1 + N_NODES * HEADS;
  float* als2 = ald1 + N_NODES * HEADS;
  float* ald2 = als2 + N_NODES * HEADS;
  int* deg      = (int*)(ald2 + N_NODES * HEADS);
  int* rowptr   = deg + N_NODES;
  int* cursor   = rowptr + N_NODES;
  int* blockSums= cursor + N_NODES;
  int* csr_src  = blockSums + 256;
  ushort* xhi   = (ushort*)(csr_src + E_EDGES);        // N*256 bf16 (x split, then elu split)
  ushort* xlo   = xhi + (size_t)N_NODES * DIM;
  ushort* bthi  = xlo + (size_t)N_NODES * DIM;         // 256*256 (W^T split)
  ushort* btlo  = bthi + DIM * DIM;

  dim3 blk(256);
  dim3 gemmGrid((N_NODES + GBM - 1) / GBM, DIM / GBM); // 391 x 2
  int nodeBlocks = (N_NODES * 64 + 255) / 256;
  int edgeThreadBlocks = (E_EDGES + 255) / 256;
  int decBlocks  = (int)(((long long)E_EDGES * 16 + 255) / 256);
  int cvtBlocks  = (N_NODES * DIM / 4 + 255) / 256;

  // ---- CSR build (graph shared by both layers) ----
  hipMemsetAsync(deg, 0, N_NODES * sizeof(int), stream);
  hipLaunchKernelGGL(histo, dim3(edgeThreadBlocks), blk, 0, stream, dst, deg);
  hipLaunchKernelGGL(scan1, dim3(SCAN_NBLK), blk, 0, stream, deg, rowptr, blockSums);
  hipLaunchKernelGGL(scan2, dim3(1), blk, 0, stream, blockSums);
  hipLaunchKernelGGL(scan3, dim3(SCAN_NBLK), blk, 0, stream, rowptr, blockSums, cursor);
  hipLaunchKernelGGL(scatter, dim3(edgeThreadBlocks), blk, 0, stream, src, dst, cursor, csr_src);

  // ---- layer 1 ----
  hipLaunchKernelGGL(cvt_split, dim3(cvtBlocks), blk, 0, stream, x, xhi, xlo, N_NODES * DIM / 4);
  hipLaunchKernelGGL(cvt_split_T, dim3(DIM * DIM / 256), blk, 0, stream, W1, bthi, btlo);
  hipLaunchKernelGGL(gemm_mfma, gemmGrid, blk, 0, stream, xhi, xlo, bthi, btlo, bufA, N_NODES);
  hipLaunchKernelGGL(attn_logits, dim3(nodeBlocks), blk, 0, stream, bufA, a_src1, a_dst1, als1, ald1);
  hipLaunchKernelGGL(agg1, dim3(nodeBlocks), blk, 0, stream, rowptr, csr_src, bufA, als1, ald1, b1, xhi, xlo);

  // ---- layer 2 ----
  hipLaunchKernelGGL(cvt_split_T, dim3(DIM * DIM / 256), blk, 0, stream, W2, bthi, btlo);
  hipLaunchKernelGGL(gemm_mfma, gemmGrid, blk, 0, stream, xhi, xlo, bthi, btlo, bufA, N_NODES);
  hipLaunchKernelGGL(attn_logits, dim3(nodeBlocks), blk, 0, stream, bufA, a_src2, a_dst2, als2, ald2);
  hipLaunchKernelGGL(agg2, dim3(nodeBlocks), blk, 0, stream, rowptr, csr_src, bufA, als2, ald2, b2, zlat);

  // ---- decoder ----
  hipLaunchKernelGGL(decoder, dim3(decBlocks), blk, 0, stream, src, dst, zlat, logits);
}

// Round 4
// 417.310 us; speedup vs baseline: 13.8094x; 1.2113x over previous
//
#include <hip/hip_runtime.h>
#include <math.h>

#define N_NODES 50000
#define E_EDGES 800000
#define DIM 256      // IN_DIM = HID = 256 (= H*O for both layers)
#define HEADS 4
#define HO 64        // per-head output width (O1 = LAT = 64)
#define NEG_SLOPE 0.2f
#define SCAN_NBLK ((N_NODES + 255) / 256)   // 196

typedef __attribute__((ext_vector_type(8))) short bf16x8;
typedef __attribute__((ext_vector_type(4))) float f32x4;

static __device__ inline ushort f2bf(float f) {
  union { float f; unsigned u; } v; v.f = f;
  unsigned r = (v.u + 0x7fff + ((v.u >> 16) & 1)) >> 16;  // RTNE
  return (ushort)r;
}
static __device__ inline float bf2f(ushort h) {
  union { unsigned u; float f; } v; v.u = ((unsigned)h) << 16;
  return v.f;
}

// W (256x256) fp32 -> W^T split into bf16 hi + lo
__global__ __launch_bounds__(256) void cvt_split_T(const float* __restrict__ W,
                                                   ushort* __restrict__ bthi,
                                                   ushort* __restrict__ btlo) {
  int idx = blockIdx.x * 256 + threadIdx.x;   // 65536 threads
  int k = idx >> 8, n = idx & 255;
  float v = W[idx];                            // W[k][n]
  ushort h = f2bf(v);
  ushort l = f2bf(v - bf2f(h));
  bthi[n * 256 + k] = h;
  btlo[n * 256 + k] = l;
}

// ---------------- split-bf16 MFMA GEMM: Cbf16(Mx256) = A_f32 @ (Bhi+Blo) ----------------
// A fp32, split into hi/lo during LDS staging. BT pre-transposed+split.
// 128x128 tile, 4 waves, 16x16x32 MFMA, 3 passes (hh, hl, lh).
#define GBM 128
#define GBK 32
#define LDK 40   // padded LDS k-stride (ushorts): 80B rows, 2-way banks max

__global__ __launch_bounds__(256) void gemm_mfma(const float* __restrict__ A,
                                                 const ushort* __restrict__ Bhi,
                                                 const ushort* __restrict__ Blo,
                                                 ushort* __restrict__ Cbf, int M) {
  __shared__ __align__(16) ushort As[2][GBM][LDK];
  __shared__ __align__(16) ushort Bs[2][GBM][LDK];
  const int tid = threadIdx.x;
  const int lane = tid & 63;
  const int wave = tid >> 6;
  const int row0 = blockIdx.x * GBM;
  const int col0 = blockIdx.y * GBM;
  const int wm = (wave & 1) * 64;
  const int wn = (wave >> 1) * 64;
  const int rA = lane & 15;
  const int kb = (lane >> 4) * 8;

  f32x4 acc[4][4] = {};

  for (int k0 = 0; k0 < DIM; k0 += GBK) {
    // A tile: 128 rows x 32 fp32 -> hi/lo bf16. 1024 float4 chunks, 4 per thread.
#pragma unroll
    for (int qq = 0; qq < 4; ++qq) {
      int q = tid + qq * 256;
      int r = q >> 3, c = q & 7;
      int grow = row0 + r;
      float4 v = make_float4(0.f, 0.f, 0.f, 0.f);
      if (grow < M) v = *(const float4*)&A[(size_t)grow * DIM + k0 + c * 4];
      ushort4 h, l;
      h.x = f2bf(v.x); l.x = f2bf(v.x - bf2f(h.x));
      h.y = f2bf(v.y); l.y = f2bf(v.y - bf2f(h.y));
      h.z = f2bf(v.z); l.z = f2bf(v.z - bf2f(h.z));
      h.w = f2bf(v.w); l.w = f2bf(v.w - bf2f(h.w));
      *(ushort4*)&As[0][r][c * 4] = h;
      *(ushort4*)&As[1][r][c * 4] = l;
    }
    // B tile: 128 rows x 32 bf16 per plane. 512 chunks of 8, 2 per thread.
#pragma unroll
    for (int qq = 0; qq < 2; ++qq) {
      int q = tid + qq * 256;
      int r = q >> 2, c = q & 3;
      bf16x8 wh = *(const bf16x8*)&Bhi[(size_t)(col0 + r) * DIM + k0 + c * 8];
      bf16x8 wl = *(const bf16x8*)&Blo[(size_t)(col0 + r) * DIM + k0 + c * 8];
      *(bf16x8*)&Bs[0][r][c * 8] = wh;
      *(bf16x8*)&Bs[1][r][c * 8] = wl;
    }
    __syncthreads();

    bf16x8 af[2][4], bfr[2][4];
#pragma unroll
    for (int mi = 0; mi < 4; ++mi) {
      af[0][mi] = *(const bf16x8*)&As[0][wm + mi * 16 + rA][kb];
      af[1][mi] = *(const bf16x8*)&As[1][wm + mi * 16 + rA][kb];
    }
#pragma unroll
    for (int ni = 0; ni < 4; ++ni) {
      bfr[0][ni] = *(const bf16x8*)&Bs[0][wn + ni * 16 + rA][kb];
      bfr[1][ni] = *(const bf16x8*)&Bs[1][wn + ni * 16 + rA][kb];
    }
#pragma unroll
    for (int mi = 0; mi < 4; ++mi)
#pragma unroll
      for (int ni = 0; ni < 4; ++ni) {
        acc[mi][ni] = __builtin_amdgcn_mfma_f32_16x16x32_bf16(af[0][mi], bfr[0][ni], acc[mi][ni], 0, 0, 0);
        acc[mi][ni] = __builtin_amdgcn_mfma_f32_16x16x32_bf16(af[0][mi], bfr[1][ni], acc[mi][ni], 0, 0, 0);
        acc[mi][ni] = __builtin_amdgcn_mfma_f32_16x16x32_bf16(af[1][mi], bfr[0][ni], acc[mi][ni], 0, 0, 0);
      }
    __syncthreads();
  }

  // C/D layout: col = lane&15, row = (lane>>4)*4 + reg. Emit bf16.
#pragma unroll
  for (int mi = 0; mi < 4; ++mi) {
    int rbase = row0 + wm + mi * 16 + (lane >> 4) * 4;
#pragma unroll
    for (int ni = 0; ni < 4; ++ni) {
      int col = col0 + wn + ni * 16 + (lane & 15);
#pragma unroll
      for (int r = 0; r < 4; ++r) {
        int row = rbase + r;
        if (row < M) Cbf[(size_t)row * DIM + col] = f2bf(acc[mi][ni][r]);
      }
    }
  }
}

// ---------------- per-node attention logits (bf16 h) ----------------
__global__ __launch_bounds__(256) void attn_logits(const ushort* __restrict__ h,
                                                   const float* __restrict__ a_src,
                                                   const float* __restrict__ a_dst,
                                                   float* __restrict__ al_s,
                                                   float* __restrict__ al_d) {
  int gid = blockIdx.x * blockDim.x + threadIdx.x;
  int node = gid >> 6;
  int lane = threadIdx.x & 63;
  if (node >= N_NODES) return;
  ushort4 hv = *(const ushort4*)&h[(size_t)node * DIM + lane * 4];
  float4 as = *(const float4*)&a_src[lane * 4];
  float4 ad = *(const float4*)&a_dst[lane * 4];
  float h0 = bf2f(hv.x), h1 = bf2f(hv.y), h2 = bf2f(hv.z), h3 = bf2f(hv.w);
  float s = h0 * as.x + h1 * as.y + h2 * as.z + h3 * as.w;
  float d = h0 * ad.x + h1 * ad.y + h2 * ad.z + h3 * ad.w;
#pragma unroll
  for (int off = 8; off >= 1; off >>= 1) {
    s += __shfl_xor(s, off, 64);
    d += __shfl_xor(d, off, 64);
  }
  if ((lane & 15) == 0) {
    int head = lane >> 4;
    al_s[node * HEADS + head] = s;
    al_d[node * HEADS + head] = d;
  }
}

// ---------------- CSR build ----------------
__global__ __launch_bounds__(256) void histo(const int* __restrict__ dst, int* __restrict__ deg) {
  int e = blockIdx.x * blockDim.x + threadIdx.x;
  if (e < E_EDGES) atomicAdd(&deg[dst[e]], 1);
}

__global__ __launch_bounds__(256) void scan1(const int* __restrict__ deg,
                                             int* __restrict__ excl,
                                             int* __restrict__ blockSums) {
  __shared__ int tmp[256];
  int i = blockIdx.x * 256 + threadIdx.x;
  int v = (i < N_NODES) ? deg[i] : 0;
  tmp[threadIdx.x] = v;
  __syncthreads();
  for (int off = 1; off < 256; off <<= 1) {
    int t = (threadIdx.x >= off) ? tmp[threadIdx.x - off] : 0;
    __syncthreads();
    tmp[threadIdx.x] += t;
    __syncthreads();
  }
  int incl = tmp[threadIdx.x];
  if (i < N_NODES) excl[i] = incl - v;
  if (threadIdx.x == 255) blockSums[blockIdx.x] = incl;
}

__global__ __launch_bounds__(256) void scan2(int* __restrict__ blockSums) {
  __shared__ int tmp[256];
  int i = threadIdx.x;
  int v = (i < SCAN_NBLK) ? blockSums[i] : 0;
  tmp[i] = v;
  __syncthreads();
  for (int off = 1; off < 256; off <<= 1) {
    int t = (i >= off) ? tmp[i - off] : 0;
    __syncthreads();
    tmp[i] += t;
    __syncthreads();
  }
  if (i < SCAN_NBLK) blockSums[i] = tmp[i] - v;  // exclusive
}

__global__ __launch_bounds__(256) void scan3(int* __restrict__ excl,
                                             const int* __restrict__ blockSums,
                                             int* __restrict__ cursor) {
  int i = blockIdx.x * 256 + threadIdx.x;
  if (i < N_NODES) {
    int r = excl[i] + blockSums[blockIdx.x];
    excl[i] = r;
    cursor[i] = r;
  }
}

__global__ __launch_bounds__(256) void scatter(const int* __restrict__ src,
                                               const int* __restrict__ dst,
                                               int* __restrict__ cursor,
                                               int* __restrict__ csr_src) {
  int e = blockIdx.x * blockDim.x + threadIdx.x;
  if (e >= E_EDGES) return;
  int pos = atomicAdd(&cursor[dst[e]], 1);
  csr_src[pos] = src[e];
}

// ---------------- aggregation core: half-wave per edge, bf16 h rows ----------------
// lane: li = lane&31, half = lane>>5; lane covers 8 cols c0 = li*8; head = li>>3.
// virtual edge index it == deg is the self-loop.
#define AGG_BODY(S)                                                         \
  {                                                                         \
    float e0 = als[(S) * HEADS + head] + aldv;                              \
    e0 = e0 > 0.f ? e0 : NEG_SLOPE * e0;                                    \
    float p = __expf(e0);                                                   \
    bf16x8 hv = *(const bf16x8*)&hbf[(size_t)(S) * DIM + c0];               \
    den += p;                                                               \
    acc[0] += p * bf2f((ushort)hv[0]);                                      \
    acc[1] += p * bf2f((ushort)hv[1]);                                      \
    acc[2] += p * bf2f((ushort)hv[2]);                                      \
    acc[3] += p * bf2f((ushort)hv[3]);                                      \
    acc[4] += p * bf2f((ushort)hv[4]);                                      \
    acc[5] += p * bf2f((ushort)hv[5]);                                      \
    acc[6] += p * bf2f((ushort)hv[6]);                                      \
    acc[7] += p * bf2f((ushort)hv[7]);                                      \
  }

// layer-1: finalize = +bias, ELU -> fp32 x2
__global__ __launch_bounds__(256) void agg1(const int* __restrict__ rowptr,
                                            const int* __restrict__ csr_src,
                                            const ushort* __restrict__ hbf,
                                            const float* __restrict__ als,
                                            const float* __restrict__ ald,
                                            const float* __restrict__ bias,
                                            float* __restrict__ x2) {
  int gid = blockIdx.x * blockDim.x + threadIdx.x;
  int node = gid >> 6;
  if (node >= N_NODES) return;
  int lane = threadIdx.x & 63;
  int li = lane & 31, half = lane >> 5;
  int head = li >> 3;
  int c0 = li * 8;
  int rs = rowptr[node];
  int deg = ((node < N_NODES - 1) ? rowptr[node + 1] : E_EDGES) - rs;
  float aldv = ald[node * HEADS + head];
  float den = 0.f;
  float acc[8] = {};
  int total = deg + 1;
  int it = half;
  for (; it + 2 < total; it += 4) {           // 2 edges per lane in flight
    int s0 = csr_src[rs + it];                // it < deg guaranteed here
    int s1 = (it + 2 < deg) ? csr_src[rs + it + 2] : node;
    AGG_BODY(s0)
    AGG_BODY(s1)
  }
  for (; it < total; it += 2) {
    int s0 = (it < deg) ? csr_src[rs + it] : node;
    AGG_BODY(s0)
  }
  den += __shfl_xor(den, 32, 64);
#pragma unroll
  for (int j = 0; j < 8; ++j) acc[j] += __shfl_xor(acc[j], 32, 64);
  if (half == 0) {
    float inv = 1.f / den;
    float r[8];
#pragma unroll
    for (int j = 0; j < 8; ++j) {
      r[j] = acc[j] * inv + bias[c0 + j];
      r[j] = r[j] > 0.f ? r[j] : expm1f(r[j]);   // ELU
    }
    *(float4*)&x2[(size_t)node * DIM + c0] = make_float4(r[0], r[1], r[2], r[3]);
    *(float4*)&x2[(size_t)node * DIM + c0 + 4] = make_float4(r[4], r[5], r[6], r[7]);
  }
}

// layer-2: finalize = mean over heads, +b2 -> fp32 z (N x 64)
__global__ __launch_bounds__(256) void agg2(const int* __restrict__ rowptr,
                                            const int* __restrict__ csr_src,
                                            const ushort* __restrict__ hbf,
                                            const float* __restrict__ als,
                                            const float* __restrict__ ald,
                                            const float* __restrict__ b2,
                                            float* __restrict__ z) {
  int gid = blockIdx.x * blockDim.x + threadIdx.x;
  int node = gid >> 6;
  if (node >= N_NODES) return;
  int lane = threadIdx.x & 63;
  int li = lane & 31, half = lane >> 5;
  int head = li >> 3;
  int c0 = li * 8;
  int rs = rowptr[node];
  int deg = ((node < N_NODES - 1) ? rowptr[node + 1] : E_EDGES) - rs;
  float aldv = ald[node * HEADS + head];
  float den = 0.f;
  float acc[8] = {};
  int total = deg + 1;
  int it = half;
  for (; it + 2 < total; it += 4) {
    int s0 = csr_src[rs + it];
    int s1 = (it + 2 < deg) ? csr_src[rs + it + 2] : node;
    AGG_BODY(s0)
    AGG_BODY(s1)
  }
  for (; it < total; it += 2) {
    int s0 = (it < deg) ? csr_src[rs + it] : node;
    AGG_BODY(s0)
  }
  den += __shfl_xor(den, 32, 64);
#pragma unroll
  for (int j = 0; j < 8; ++j) acc[j] += __shfl_xor(acc[j], 32, 64);
  float inv = 1.f / den;
  float r[8];
#pragma unroll
  for (int j = 0; j < 8; ++j) {
    r[j] = acc[j] * inv;
    r[j] += __shfl_xor(r[j], 8, 64);    // head 0<->1 (and 2<->3)
    r[j] += __shfl_xor(r[j], 16, 64);   // heads (0,1)<->(2,3)
  }
  if (lane < 8) {   // half==0, li<8: cols li*8..li*8+7 of the 64-wide z row
    int zc = li * 8;
    float4 v0 = make_float4(r[0] * 0.25f + b2[zc + 0], r[1] * 0.25f + b2[zc + 1],
                            r[2] * 0.25f + b2[zc + 2], r[3] * 0.25f + b2[zc + 3]);
    float4 v1 = make_float4(r[4] * 0.25f + b2[zc + 4], r[5] * 0.25f + b2[zc + 5],
                            r[6] * 0.25f + b2[zc + 6], r[7] * 0.25f + b2[zc + 7]);
    *(float4*)&z[(size_t)node * HO + zc] = v0;
    *(float4*)&z[(size_t)node * HO + zc + 4] = v1;
  }
}

// ---------------- decoder ----------------
__global__ __launch_bounds__(256) void decoder(const int* __restrict__ src,
                                               const int* __restrict__ dst,
                                               const float* __restrict__ z,
                                               float* __restrict__ out) {
  long long gid = (long long)blockIdx.x * blockDim.x + threadIdx.x;
  int e = (int)(gid >> 4);
  if (e >= E_EDGES) return;
  int l = threadIdx.x & 15;
  int s = src[e];
  int d = dst[e];
  float4 a = *(const float4*)&z[(size_t)s * HO + l * 4];
  float4 b = *(const float4*)&z[(size_t)d * HO + l * 4];
  float v = a.x * b.x + a.y * b.y + a.z * b.z + a.w * b.w;
#pragma unroll
  for (int off = 8; off >= 1; off >>= 1) v += __shfl_xor(v, off, 64);
  if (l == 0) out[e] = v;
}

extern "C" void kernel_launch(void* const* d_in, const int* in_sizes, int n_in,
                              void* d_out, int out_size, void* d_ws, size_t ws_size,
                              hipStream_t stream) {
  const float* x      = (const float*)d_in[0];
  const int*   ei     = (const int*)d_in[1];
  const float* W1     = (const float*)d_in[2];
  const float* a_src1 = (const float*)d_in[3];
  const float* a_dst1 = (const float*)d_in[4];
  const float* b1     = (const float*)d_in[5];
  const float* W2     = (const float*)d_in[6];
  const float* a_src2 = (const float*)d_in[7];
  const float* a_dst2 = (const float*)d_in[8];
  const float* b2     = (const float*)d_in[9];
  const int* src = ei;
  const int* dst = ei + E_EDGES;
  float* logits = (float*)d_out;

  float* x2fp = (float*)d_ws;                          // N*256 fp32 (elu(gat1))
  float* zlat = x2fp + (size_t)N_NODES * DIM;          // N*64
  float* als1 = zlat + (size_t)N_NODES * HO;
  float* ald1 = als1 + N_NODES * HEADS;
  float* als2 = ald1 + N_NODES * HEADS;
  float* ald2 = als2 + N_NODES * HEADS;
  int* deg      = (int*)(ald2 + N_NODES * HEADS);
  int* rowptr   = deg + N_NODES;
  int* cursor   = rowptr + N_NODES;
  int* blockSums= cursor + N_NODES;
  int* csr_src  = blockSums + 256;
  ushort* hbf   = (ushort*)(csr_src + E_EDGES);        // N*256 bf16 (h1, then h2)
  ushort* bthi  = hbf + (size_t)N_NODES * DIM;         // 256*256 (W^T split)
  ushort* btlo  = bthi + DIM * DIM;

  dim3 blk(256);
  dim3 gemmGrid((N_NODES + GBM - 1) / GBM, DIM / GBM); // 391 x 2
  int nodeBlocks = (N_NODES * 64 + 255) / 256;
  int edgeThreadBlocks = (E_EDGES + 255) / 256;
  int decBlocks  = (int)(((long long)E_EDGES * 16 + 255) / 256);

  // ---- CSR build (graph shared by both layers) ----
  hipMemsetAsync(deg, 0, N_NODES * sizeof(int), stream);
  hipLaunchKernelGGL(histo, dim3(edgeThreadBlocks), blk, 0, stream, dst, deg);
  hipLaunchKernelGGL(scan1, dim3(SCAN_NBLK), blk, 0, stream, deg, rowptr, blockSums);
  hipLaunchKernelGGL(scan2, dim3(1), blk, 0, stream, blockSums);
  hipLaunchKernelGGL(scan3, dim3(SCAN_NBLK), blk, 0, stream, rowptr, blockSums, cursor);
  hipLaunchKernelGGL(scatter, dim3(edgeThreadBlocks), blk, 0, stream, src, dst, cursor, csr_src);

  // ---- layer 1 ----
  hipLaunchKernelGGL(cvt_split_T, dim3(DIM * DIM / 256), blk, 0, stream, W1, bthi, btlo);
  hipLaunchKernelGGL(gemm_mfma, gemmGrid, blk, 0, stream, x, bthi, btlo, hbf, N_NODES);
  hipLaunchKernelGGL(attn_logits, dim3(nodeBlocks), blk, 0, stream, hbf, a_src1, a_dst1, als1, ald1);
  hipLaunchKernelGGL(agg1, dim3(nodeBlocks), blk, 0, stream, rowptr, csr_src, hbf, als1, ald1, b1, x2fp);

  // ---- layer 2 ----
  hipLaunchKernelGGL(cvt_split_T, dim3(DIM * DIM / 256), blk, 0, stream, W2, bthi, btlo);
  hipLaunchKernelGGL(gemm_mfma, gemmGrid, blk, 0, stream, x2fp, bthi, btlo, hbf, N_NODES);
  hipLaunchKernelGGL(attn_logits, dim3(nodeBlocks), blk, 0, stream, hbf, a_src2, a_dst2, als2, ald2);
  hipLaunchKernelGGL(agg2, dim3(nodeBlocks), blk, 0, stream, rowptr, csr_src, hbf, als2, ald2, b2, zlat);

  // ---- decoder ----
  hipLaunchKernelGGL(decoder, dim3(decBlocks), blk, 0, stream, src, dst, zlat, logits);
}